// Round 1
// baseline (500.986 us; speedup 1.0000x reference)
//
#include <hip/hip_runtime.h>
#include <hip/hip_bf16.h>

// EquivariantLayerNorm: segmented (per-block) LayerNorm over H and edge_attr,
// plus equivariant coordinate rescale on Z.
//
// Inputs (setup_inputs order, all f32 except ids):
//  0: H        [N,128]   1: Z       [N,3]    2: edge_attr [E,64]
//  3: sigma    [1,3]     4: ln_H_w  [128]    5: ln_H_b    [128]
//  6: ln_E_w   [64]      7: ln_E_b  [64]     8: block_id  [N] (sorted i32)
//  9: edge_id  [2,E] i32
// Output: concat(H_out [N*128], Z_out [N*3], E_out [E*64], rescale [NB*3])

#define EPS_LN 1e-12f
#define EPS_STD 1e-8f

// ---------------- node-side: one workgroup per block (block_id sorted) ------
__global__ void node_kernel(const float* __restrict__ H,
                            const float* __restrict__ Z,
                            const float* __restrict__ sigma,
                            const float* __restrict__ wH,
                            const float* __restrict__ bH,
                            const int* __restrict__ block_id, int N,
                            float* __restrict__ H_out,
                            float* __restrict__ Z_out,
                            float* __restrict__ rescale_out) {
  const int b = blockIdx.x;
  __shared__ int s_start, s_end;
  if (threadIdx.x == 0) {
    // lower_bound(block_id, b) and lower_bound(block_id, b+1)
    int lo = 0, hi = N;
    while (lo < hi) { int mid = (lo + hi) >> 1; if (block_id[mid] < b) lo = mid + 1; else hi = mid; }
    s_start = lo;
    hi = N;
    while (lo < hi) { int mid = (lo + hi) >> 1; if (block_id[mid] < b + 1) lo = mid + 1; else hi = mid; }
    s_end = lo;
  }
  __syncthreads();
  const int start = s_start, end = s_end;
  const int c = end - start;
  const float cf = (float)c;
  const float denom = fmaxf(cf, 1.0f);
  const int f = threadIdx.x;  // feature, 0..127

  // per-feature H stats
  float sum = 0.0f, sq = 0.0f;
  for (int i = start; i < end; ++i) {
    float x = H[(size_t)i * 128 + f];
    sum += x;
    sq = fmaf(x, x, sq);
  }
  const float u = sum / denom;
  const float var = fmaxf(sq / denom - u * u, 0.0f);
  const float rstd = rsqrtf(var + EPS_LN);
  const float w = wH[f], bb = bH[f];
  for (int i = start; i < end; ++i) {
    float x = H[(size_t)i * 128 + f];
    H_out[(size_t)i * 128 + f] = fmaf(w * (x - u), rstd, bb);
  }

  // Z path: threads 0..2 handle axis f
  __shared__ float s_zc[3], s_sd[3], s_sdd[3];
  if (f < 3) {
    float zs = 0.0f;
    for (int i = start; i < end; ++i) zs += Z[(size_t)i * 3 + f];
    float zc = zs / denom;
    s_zc[f] = zc;
    float sd = 0.0f, sdd = 0.0f;
    for (int i = start; i < end; ++i) {
      float d = Z[(size_t)i * 3 + f] - zc;
      sd += d;
      sdd = fmaf(d, d, sdd);
    }
    s_sd[f] = sd;
    s_sdd[f] = sdd;
  }
  __syncthreads();
  if (f < 3) {
    const float cnt = 3.0f * cf;
    const float m = (s_sd[0] + s_sd[1] + s_sd[2]) / fmaxf(cnt, 1.0f);
    float ss = (s_sdd[0] + s_sdd[1] + s_sdd[2]) - cnt * m * m;  // Sum (d-m)^2
    ss = fmaxf(ss, 0.0f);
    const float var_Ez = sqrtf(ss / fmaxf(cnt - 1.0f, 1.0f)) + EPS_STD;
    const float resc = sigma[f] / var_Ez;
    rescale_out[(size_t)b * 3 + f] = resc;
    const float zc = s_zc[f];
    for (int i = start; i < end; ++i) {
      float d = Z[(size_t)i * 3 + f] - zc;
      Z_out[(size_t)i * 3 + f] = fmaf(d, resc, zc);
    }
  }
}

// ---------------- edge-side: counting sort by segment, then per-seg LN ------
__global__ void zero_kernel(int* __restrict__ p, int n) {
  int i = blockIdx.x * blockDim.x + threadIdx.x;
  if (i < n) p[i] = 0;
}

__global__ void edge_seg_kernel(const int* __restrict__ edge_id,
                                const int* __restrict__ block_id, int E,
                                int* __restrict__ seg, int* __restrict__ count) {
  int e = blockIdx.x * blockDim.x + threadIdx.x;
  if (e >= E) return;
  int src = edge_id[e];         // row 0 of edge_id [2,E]
  int s = block_id[src];
  seg[e] = s;
  atomicAdd(&count[s], 1);
}

__global__ void scan_kernel(const int* __restrict__ count, int NB,
                            int* __restrict__ offset, int* __restrict__ cursor) {
  __shared__ int lds[1024];
  const int t = threadIdx.x;
  const int per = (NB + 1023) / 1024;
  const int lo = t * per;
  const int hi = min(lo + per, NB);
  int s = 0;
  for (int i = lo; i < hi; ++i) s += count[i];
  lds[t] = s;
  __syncthreads();
  // Hillis-Steele inclusive scan over 1024 partials
  for (int d = 1; d < 1024; d <<= 1) {
    int v = (t >= d) ? lds[t - d] : 0;
    __syncthreads();
    lds[t] += v;
    __syncthreads();
  }
  int excl = lds[t] - s;  // exclusive prefix of this thread's chunk
  for (int i = lo; i < hi; ++i) {
    offset[i] = excl;
    cursor[i] = excl;
    excl += count[i];
  }
  if (t == 1023) offset[NB] = lds[1023];
}

__global__ void scatter_kernel(const int* __restrict__ seg, int E,
                               int* __restrict__ cursor, int* __restrict__ order) {
  int e = blockIdx.x * blockDim.x + threadIdx.x;
  if (e >= E) return;
  int pos = atomicAdd(&cursor[seg[e]], 1);
  order[pos] = e;
}

__global__ void edge_ln_kernel(const float* __restrict__ EA,
                               const float* __restrict__ wE,
                               const float* __restrict__ bE,
                               const int* __restrict__ offset,
                               const int* __restrict__ order,
                               float* __restrict__ E_out) {
  const int b = blockIdx.x;
  const int start = offset[b], end = offset[b + 1];
  const int f = threadIdx.x;  // feature 0..63
  float sum = 0.0f, sq = 0.0f;
  for (int i = start; i < end; ++i) {
    int e = order[i];
    float x = EA[(size_t)e * 64 + f];
    sum += x;
    sq = fmaf(x, x, sq);
  }
  const float cf = (float)(end - start);
  const float denom = fmaxf(cf, 1.0f);
  const float u = sum / denom;
  const float rstd = rsqrtf(fmaxf(sq / denom - u * u, 0.0f) + EPS_LN);
  const float w = wE[f], bb = bE[f];
  for (int i = start; i < end; ++i) {
    int e = order[i];
    float x = EA[(size_t)e * 64 + f];
    E_out[(size_t)e * 64 + f] = fmaf(w * (x - u), rstd, bb);
  }
}

extern "C" void kernel_launch(void* const* d_in, const int* in_sizes, int n_in,
                              void* d_out, int out_size, void* d_ws, size_t ws_size,
                              hipStream_t stream) {
  const float* H        = (const float*)d_in[0];
  const float* Z        = (const float*)d_in[1];
  const float* EA       = (const float*)d_in[2];
  const float* sigma    = (const float*)d_in[3];
  const float* ln_H_w   = (const float*)d_in[4];
  const float* ln_H_b   = (const float*)d_in[5];
  const float* ln_E_w   = (const float*)d_in[6];
  const float* ln_E_b   = (const float*)d_in[7];
  const int*   block_id = (const int*)d_in[8];
  const int*   edge_id  = (const int*)d_in[9];

  const int N = in_sizes[0] / 128;
  const int E = in_sizes[2] / 64;
  // NB from output layout: out = N*128 + N*3 + E*64 + NB*3
  const int NB = (int)(((long long)out_size - (long long)N * 131 - (long long)E * 64) / 3);

  float* out = (float*)d_out;
  float* H_out   = out;
  float* Z_out   = out + (size_t)N * 128;
  float* E_out   = out + (size_t)N * 128 + (size_t)N * 3;
  float* resc    = out + (size_t)N * 128 + (size_t)N * 3 + (size_t)E * 64;

  // workspace layout (ints)
  int* seg    = (int*)d_ws;                 // E
  int* order  = seg + E;                    // E
  int* count  = order + E;                  // NB
  int* offset = count + NB;                 // NB+1
  int* cursor = offset + NB + 1;            // NB

  // 1. zero segment counts
  zero_kernel<<<(NB + 255) / 256, 256, 0, stream>>>(count, NB);
  // 2. node-side: H LN + Z rescale + rescale output
  node_kernel<<<NB, 128, 0, stream>>>(H, Z, sigma, ln_H_w, ln_H_b, block_id, N,
                                      H_out, Z_out, resc);
  // 3. edge segment ids + histogram
  edge_seg_kernel<<<(E + 255) / 256, 256, 0, stream>>>(edge_id, block_id, E, seg, count);
  // 4. exclusive scan of counts
  scan_kernel<<<1, 1024, 0, stream>>>(count, NB, offset, cursor);
  // 5. scatter edge indices into segment-sorted order
  scatter_kernel<<<(E + 255) / 256, 256, 0, stream>>>(seg, E, cursor, order);
  // 6. per-segment edge LN
  edge_ln_kernel<<<NB, 64, 0, stream>>>(EA, ln_E_w, ln_E_b, offset, order, E_out);
}

// Round 2
// 392.068 us; speedup vs baseline: 1.2778x; 1.2778x over previous
//
#include <hip/hip_runtime.h>
#include <hip/hip_bf16.h>

// EquivariantLayerNorm: segmented (per-block) LayerNorm over H and edge_attr,
// plus equivariant coordinate rescale on Z.
//
// Inputs (setup_inputs order, all f32 except ids):
//  0: H        [N,128]   1: Z       [N,3]    2: edge_attr [E,64]
//  3: sigma    [1,3]     4: ln_H_w  [128]    5: ln_H_b    [128]
//  6: ln_E_w   [64]      7: ln_E_b  [64]     8: block_id  [N] (sorted i32)
//  9: edge_id  [2,E] i32
// Output: concat(H_out [N*128], Z_out [N*3], E_out [E*64], rescale [NB*3])

#define EPS_LN 1e-12f
#define EPS_STD 1e-8f

__device__ __forceinline__ float4 f4zero() { return make_float4(0.f, 0.f, 0.f, 0.f); }

// ---------- segment offsets from sorted block_id (replaces binary search) ---
__global__ void node_off_kernel(const int* __restrict__ block_id, int N, int NB,
                                int* __restrict__ node_off) {
  int i = blockIdx.x * blockDim.x + threadIdx.x;
  if (i >= N) return;
  int cur = block_id[i];
  int prev = (i == 0) ? -1 : block_id[i - 1];
  for (int b = prev + 1; b <= cur; ++b) node_off[b] = i;
  if (i == N - 1) {
    for (int b = cur + 1; b <= NB; ++b) node_off[b] = N;
  }
}

// ---------------- node-side: one 256-thread workgroup per block -------------
// 8 node-slots in flight, float4 per lane (32 lane-groups x 4 = 128 features).
__global__ void node_kernel(const float4* __restrict__ H4,
                            const float* __restrict__ Z,
                            const float* __restrict__ sigma,
                            const float* __restrict__ wH,
                            const float* __restrict__ bH,
                            const int* __restrict__ node_off,
                            float4* __restrict__ H_out4,
                            float* __restrict__ Z_out,
                            float* __restrict__ rescale_out) {
  const int b = blockIdx.x;
  const int start = node_off[b], end = node_off[b + 1];
  const int c = end - start;
  const float denom = fmaxf((float)c, 1.0f);
  const int fg = threadIdx.x & 31;    // feature group: floats [fg*4, fg*4+4)
  const int slot = threadIdx.x >> 5;  // node slot 0..7

  // --- H stats (strided over nodes, vectorized over features) ---
  float4 sum = f4zero(), sq = f4zero();
  for (int i = start + slot; i < end; i += 8) {
    float4 x = H4[(size_t)i * 32 + fg];
    sum.x += x.x; sum.y += x.y; sum.z += x.z; sum.w += x.w;
    sq.x = fmaf(x.x, x.x, sq.x); sq.y = fmaf(x.y, x.y, sq.y);
    sq.z = fmaf(x.z, x.z, sq.z); sq.w = fmaf(x.w, x.w, sq.w);
  }
  __shared__ float4 s_sum[8][32];
  __shared__ float4 s_sq[8][32];
  __shared__ float4 s_u[32], s_r[32];
  __shared__ float s_zc[3], s_sd[3], s_sdd[3];
  s_sum[slot][fg] = sum;
  s_sq[slot][fg] = sq;
  __syncthreads();

  if (slot == 0) {  // wave-0 lanes 0..31: cross-slot reduce + u/rstd
    float4 ts = s_sum[0][fg], tq = s_sq[0][fg];
    #pragma unroll
    for (int s = 1; s < 8; ++s) {
      float4 a = s_sum[s][fg], q = s_sq[s][fg];
      ts.x += a.x; ts.y += a.y; ts.z += a.z; ts.w += a.w;
      tq.x += q.x; tq.y += q.y; tq.z += q.z; tq.w += q.w;
    }
    float4 u, r;
    u.x = ts.x / denom; u.y = ts.y / denom; u.z = ts.z / denom; u.w = ts.w / denom;
    r.x = rsqrtf(fmaxf(tq.x / denom - u.x * u.x, 0.f) + EPS_LN);
    r.y = rsqrtf(fmaxf(tq.y / denom - u.y * u.y, 0.f) + EPS_LN);
    r.z = rsqrtf(fmaxf(tq.z / denom - u.z * u.z, 0.f) + EPS_LN);
    r.w = rsqrtf(fmaxf(tq.w / denom - u.w * u.w, 0.f) + EPS_LN);
    s_u[fg] = u;
    s_r[fg] = r;
  }

  // --- Z stats on wave 3 (overlaps the reduce above) ---
  const int zt = threadIdx.x - 192;  // 0..2 handle axis zt
  if (zt >= 0 && zt < 3) {
    float zs = 0.0f;
    for (int i = start; i < end; ++i) zs += Z[(size_t)i * 3 + zt];
    float zc = zs / denom;
    s_zc[zt] = zc;
    float sd = 0.0f, sdd = 0.0f;
    for (int i = start; i < end; ++i) {
      float d = Z[(size_t)i * 3 + zt] - zc;
      sd += d;
      sdd = fmaf(d, d, sdd);
    }
    s_sd[zt] = sd;
    s_sdd[zt] = sdd;
  }
  __syncthreads();

  // --- H output pass ---
  const float4 u = s_u[fg], r = s_r[fg];
  const float4 w = reinterpret_cast<const float4*>(wH)[fg];
  const float4 bb = reinterpret_cast<const float4*>(bH)[fg];
  for (int i = start + slot; i < end; i += 8) {
    float4 x = H4[(size_t)i * 32 + fg];
    float4 o;
    o.x = fmaf(w.x * (x.x - u.x), r.x, bb.x);
    o.y = fmaf(w.y * (x.y - u.y), r.y, bb.y);
    o.z = fmaf(w.z * (x.z - u.z), r.z, bb.z);
    o.w = fmaf(w.w * (x.w - u.w), r.w, bb.w);
    H_out4[(size_t)i * 32 + fg] = o;
  }

  // --- Z rescale + output (threads 192..194) ---
  if (zt >= 0 && zt < 3) {
    const float cnt3 = 3.0f * (float)c;
    const float m = (s_sd[0] + s_sd[1] + s_sd[2]) / fmaxf(cnt3, 1.0f);
    float ss = (s_sdd[0] + s_sdd[1] + s_sdd[2]) - cnt3 * m * m;
    ss = fmaxf(ss, 0.0f);
    const float var_Ez = sqrtf(ss / fmaxf(cnt3 - 1.0f, 1.0f)) + EPS_STD;
    const float resc = sigma[zt] / var_Ez;
    rescale_out[(size_t)b * 3 + zt] = resc;
    const float zc = s_zc[zt];
    for (int i = start; i < end; ++i) {
      float d = Z[(size_t)i * 3 + zt] - zc;
      Z_out[(size_t)i * 3 + zt] = fmaf(d, resc, zc);
    }
  }
}

// ---------------- edge-side: counting sort by segment, then per-seg LN ------
__global__ void zero_kernel(int* __restrict__ p, int n) {
  int i = blockIdx.x * blockDim.x + threadIdx.x;
  if (i < n) p[i] = 0;
}

__global__ void edge_seg_kernel(const int* __restrict__ edge_id,
                                const int* __restrict__ block_id, int E,
                                int* __restrict__ seg, int* __restrict__ count) {
  int e = blockIdx.x * blockDim.x + threadIdx.x;
  if (e >= E) return;
  int src = edge_id[e];  // row 0 of edge_id [2,E]
  int s = block_id[src];
  seg[e] = s;
  atomicAdd(&count[s], 1);
}

__global__ void scan_kernel(const int* __restrict__ count, int NB,
                            int* __restrict__ offset, int* __restrict__ cursor) {
  __shared__ int lds[1024];
  const int t = threadIdx.x;
  const int per = (NB + 1023) / 1024;
  const int lo = t * per;
  const int hi = min(lo + per, NB);
  int s = 0;
  for (int i = lo; i < hi; ++i) s += count[i];
  lds[t] = s;
  __syncthreads();
  for (int d = 1; d < 1024; d <<= 1) {
    int v = (t >= d) ? lds[t - d] : 0;
    __syncthreads();
    lds[t] += v;
    __syncthreads();
  }
  int excl = lds[t] - s;
  for (int i = lo; i < hi; ++i) {
    offset[i] = excl;
    cursor[i] = excl;
    excl += count[i];
  }
  if (t == 1023) offset[NB] = lds[1023];
}

__global__ void scatter_kernel(const int* __restrict__ seg, int E,
                               int* __restrict__ cursor, int* __restrict__ order) {
  int e = blockIdx.x * blockDim.x + threadIdx.x;
  if (e >= E) return;
  int pos = atomicAdd(&cursor[seg[e]], 1);
  order[pos] = e;
}

// 16 edge-slots in flight, float4 per lane (16 lane-groups x 4 = 64 features).
#define ELN_CAP 2048
__global__ void edge_ln_kernel(const float4* __restrict__ EA4,
                               const float* __restrict__ wE,
                               const float* __restrict__ bE,
                               const int* __restrict__ offset,
                               const int* __restrict__ order,
                               float4* __restrict__ E_out4) {
  const int b = blockIdx.x;
  const int start = offset[b], end = offset[b + 1];
  const int cnt = end - start;
  const int fg = threadIdx.x & 15;    // feature group: floats [fg*4, fg*4+4)
  const int slot = threadIdx.x >> 4;  // edge slot 0..15

  __shared__ int s_order[ELN_CAP];
  const int lim = min(cnt, ELN_CAP);
  for (int i = threadIdx.x; i < lim; i += 256) s_order[i] = order[start + i];
  __syncthreads();

  float4 sum = f4zero(), sq = f4zero();
  for (int i = slot; i < cnt; i += 16) {
    int e = (i < ELN_CAP) ? s_order[i] : order[start + i];
    float4 x = EA4[(size_t)e * 16 + fg];
    sum.x += x.x; sum.y += x.y; sum.z += x.z; sum.w += x.w;
    sq.x = fmaf(x.x, x.x, sq.x); sq.y = fmaf(x.y, x.y, sq.y);
    sq.z = fmaf(x.z, x.z, sq.z); sq.w = fmaf(x.w, x.w, sq.w);
  }
  __shared__ float4 s_sum[16][16];
  __shared__ float4 s_sq[16][16];
  __shared__ float4 s_u[16], s_r[16];
  s_sum[slot][fg] = sum;
  s_sq[slot][fg] = sq;
  __syncthreads();

  if (slot == 0) {
    float4 ts = s_sum[0][fg], tq = s_sq[0][fg];
    #pragma unroll
    for (int s = 1; s < 16; ++s) {
      float4 a = s_sum[s][fg], q = s_sq[s][fg];
      ts.x += a.x; ts.y += a.y; ts.z += a.z; ts.w += a.w;
      tq.x += q.x; tq.y += q.y; tq.z += q.z; tq.w += q.w;
    }
    const float denom = fmaxf((float)cnt, 1.0f);
    float4 u, r;
    u.x = ts.x / denom; u.y = ts.y / denom; u.z = ts.z / denom; u.w = ts.w / denom;
    r.x = rsqrtf(fmaxf(tq.x / denom - u.x * u.x, 0.f) + EPS_LN);
    r.y = rsqrtf(fmaxf(tq.y / denom - u.y * u.y, 0.f) + EPS_LN);
    r.z = rsqrtf(fmaxf(tq.z / denom - u.z * u.z, 0.f) + EPS_LN);
    r.w = rsqrtf(fmaxf(tq.w / denom - u.w * u.w, 0.f) + EPS_LN);
    s_u[fg] = u;
    s_r[fg] = r;
  }
  __syncthreads();

  const float4 u = s_u[fg], r = s_r[fg];
  const float4 w = reinterpret_cast<const float4*>(wE)[fg];
  const float4 bb = reinterpret_cast<const float4*>(bE)[fg];
  for (int i = slot; i < cnt; i += 16) {
    int e = (i < ELN_CAP) ? s_order[i] : order[start + i];
    float4 x = EA4[(size_t)e * 16 + fg];
    float4 o;
    o.x = fmaf(w.x * (x.x - u.x), r.x, bb.x);
    o.y = fmaf(w.y * (x.y - u.y), r.y, bb.y);
    o.z = fmaf(w.z * (x.z - u.z), r.z, bb.z);
    o.w = fmaf(w.w * (x.w - u.w), r.w, bb.w);
    E_out4[(size_t)e * 16 + fg] = o;
  }
}

extern "C" void kernel_launch(void* const* d_in, const int* in_sizes, int n_in,
                              void* d_out, int out_size, void* d_ws, size_t ws_size,
                              hipStream_t stream) {
  const float* H        = (const float*)d_in[0];
  const float* Z        = (const float*)d_in[1];
  const float* EA       = (const float*)d_in[2];
  const float* sigma    = (const float*)d_in[3];
  const float* ln_H_w   = (const float*)d_in[4];
  const float* ln_H_b   = (const float*)d_in[5];
  const float* ln_E_w   = (const float*)d_in[6];
  const float* ln_E_b   = (const float*)d_in[7];
  const int*   block_id = (const int*)d_in[8];
  const int*   edge_id  = (const int*)d_in[9];

  const int N = in_sizes[0] / 128;
  const int E = in_sizes[2] / 64;
  const int NB = (int)(((long long)out_size - (long long)N * 131 - (long long)E * 64) / 3);

  float* out = (float*)d_out;
  float* H_out = out;
  float* Z_out = out + (size_t)N * 128;
  float* E_out = out + (size_t)N * 128 + (size_t)N * 3;
  float* resc  = out + (size_t)N * 128 + (size_t)N * 3 + (size_t)E * 64;

  // workspace layout (ints)
  int* seg      = (int*)d_ws;        // E
  int* order    = seg + E;           // E
  int* count    = order + E;         // NB
  int* offset   = count + NB;        // NB+1
  int* cursor   = offset + NB + 1;   // NB
  int* node_off = cursor + NB;       // NB+1

  zero_kernel<<<(NB + 255) / 256, 256, 0, stream>>>(count, NB);
  node_off_kernel<<<(N + 255) / 256, 256, 0, stream>>>(block_id, N, NB, node_off);
  edge_seg_kernel<<<(E + 255) / 256, 256, 0, stream>>>(edge_id, block_id, E, seg, count);
  node_kernel<<<NB, 256, 0, stream>>>((const float4*)H, Z, sigma, ln_H_w, ln_H_b,
                                      node_off, (float4*)H_out, Z_out, resc);
  scan_kernel<<<1, 1024, 0, stream>>>(count, NB, offset, cursor);
  scatter_kernel<<<(E + 255) / 256, 256, 0, stream>>>(seg, E, cursor, order);
  edge_ln_kernel<<<NB, 256, 0, stream>>>((const float4*)EA, ln_E_w, ln_E_b,
                                         offset, order, (float4*)E_out);
}